// Round 5
// baseline (67.534 us; speedup 1.0000x reference)
//
#include <hip/hip_runtime.h>
#include <hip/hip_fp16.h>

#define SPAN 20
#define REPEAT 90

// pred, gt: [4, 1, 512, 512] f32. h_offsets, w_offsets: [90] i32.
// out: scalar f32 = mean |l2norm(pred_rd) - l2norm(gt_rd)| over [B,Hb,Wb,R].

constexpr int W  = 512;
constexpr int Wb = 472;           // 512 - 2*SPAN
constexpr int TJ = 64;            // output tile width  (j)
constexpr int TI = 4;             // output tile height (i); 472/4 = 118 exact
constexpr int TW = TJ + 2 * SPAN; // 104 input tile width
constexpr int TH = TI + 2 * SPAN; // 44  input tile height

__global__ __launch_bounds__(256, 4) void rd_loss_kernel(
    const float* __restrict__ pred, const float* __restrict__ gt,
    const int* __restrict__ hoff, const int* __restrict__ woff,
    float* __restrict__ out)
{
    // {p,g} packed as half2 -> one ds_read_b32 serves both arrays.
    __shared__ __half2 tile[TH * TW];   // 44*104*4 = 18304 B
    __shared__ float wsum[4];

    const int t  = threadIdx.x;
    const int bx = blockIdx.x;    // 0..7    j-tile
    const int by = blockIdx.y;    // 0..117  i-tile
    const int b  = blockIdx.z;    // 0..3    batch
    const int I0 = by * TI;
    const int J0 = bx * TJ;

    const float* pb_ = pred + b * (W * W);
    const float* gb_ = gt   + b * (W * W);

    // ---- stage input tile (rows always in range; cols clamped) ----
    for (int e = t; e < TH * TW; e += 256) {
        const int row = e / TW;
        const int col = e - row * TW;
        const int gr  = I0 + row;                      // <= 511 always
        int gc        = J0 + col; gc = gc < 511 ? gc : 511;
        const int gi  = gr * W + gc;
        tile[e] = __floats2half2_rn(pb_[gi], gb_[gi]);
    }
    __syncthreads();

    // ---- one pixel per thread: (ii, jj); lane-consecutive j -> conflict-free
    const int jj = t & 63;
    const int ii = t >> 6;                // 0..3
    const bool valid = (J0 + jj) < Wb;    // i always valid (118*4 = 472)

    const int base0 = (SPAN + ii) * TW + (SPAN + jj);
    const __half2 c0 = tile[base0];

    // ---- pass 1: read each shifted px ONCE, cache diff {dp,dg} in regs ----
    __half2 d[REPEAT];                    // 90 VGPRs
    __half2 sA = __floats2half2_rn(0.f, 0.f), sB = sA;
    #pragma unroll
    for (int r = 0; r < REPEAT; ++r) {
        const int off = hoff[r] * TW + woff[r];        // uniform (s_load+SALU)
        d[r] = __hsub2(c0, tile[base0 + off]);         // v_add + ds_read_b32
        if (r & 1) sB = __hfma2(d[r], d[r], sB);
        else       sA = __hfma2(d[r], d[r], sA);
    }
    const float ssp = __half2float(__low2half(sA))  + __half2float(__low2half(sB));
    const float ssg = __half2float(__high2half(sA)) + __half2float(__high2half(sB));

    const float invp = (ssp == 0.f) ? 1.f : rsqrtf(ssp);
    const float invg = (ssg == 0.f) ? 1.f : rsqrtf(ssg);

    // |dp*invp - dg*invg| = invp * |dp - (invg/invp)*dg|
    const __half nr = __float2half(-(invg / invp));

    // ---- pass 2: pure register math, 2 VALU per shift ----
    __half aA = __float2half(0.f), aB = aA;
    #pragma unroll
    for (int r = 0; r < REPEAT; ++r) {
        // s = dp + nr*dg  (dp = lo half, dg = hi half; op_sel picks halves)
        const __half s = __hfma(nr, __high2half(d[r]), __low2half(d[r]));
        if (r & 1) aB = __hadd(aB, __habs(s));
        else       aA = __hadd(aA, __habs(s));
    }
    const float l = invp * (__half2float(aA) + __half2float(aB));

    float lsum = valid ? l : 0.f;

    // ---- reduction: wave shuffle -> LDS -> one atomic per block ----
    #pragma unroll
    for (int o = 32; o > 0; o >>= 1) lsum += __shfl_down(lsum, o, 64);

    const int lane = t & 63;
    const int wid  = t >> 6;
    if (lane == 0) wsum[wid] = lsum;
    __syncthreads();

    if (t == 0) {
        const float s = wsum[0] + wsum[1] + wsum[2] + wsum[3];
        constexpr float scale = 1.0f / (4.0f * 472.0f * 472.0f * 90.0f);
        atomicAdd(out, s * scale);
    }
}

extern "C" void kernel_launch(void* const* d_in, const int* in_sizes, int n_in,
                              void* d_out, int out_size, void* d_ws, size_t ws_size,
                              hipStream_t stream) {
    const float* pred = (const float*)d_in[0];
    const float* gt   = (const float*)d_in[1];
    const int* hoff   = (const int*)d_in[2];
    const int* woff   = (const int*)d_in[3];
    float* out = (float*)d_out;

    // Harness poisons d_out once and never re-poisons between graph replays:
    // zero it on-stream every call (graph-capturable).
    hipMemsetAsync(out, 0, sizeof(float), stream);

    dim3 grid(8, 118, 4);   // (472/64 ceil, 472/4, B)
    rd_loss_kernel<<<grid, 256, 0, stream>>>(pred, gt, hoff, woff, out);
}

// Round 6
// 45.487 us; speedup vs baseline: 1.4847x; 1.4847x over previous
//
#include <hip/hip_runtime.h>
#include <hip/hip_fp16.h>

#define SPAN 20
#define REPEAT 90

// pred, gt: [4, 1, 512, 512] f32. h_offsets, w_offsets: [90] i32.
// out: scalar f32 = mean |l2norm(pred_rd) - l2norm(gt_rd)| over [B,Hb,Wb,R].

constexpr int W  = 512;
constexpr int Wb = 472;           // 512 - 2*SPAN
constexpr int TJ = 64;            // output tile width  (j)
constexpr int TI = 8;             // output tile height (i); 472/8 = 59 exact
constexpr int TW = TJ + 2 * SPAN; // 104 input tile width
constexpr int TH = TI + 2 * SPAN; // 48  input tile height

__global__ __launch_bounds__(512, 4) void rd_loss_kernel(
    const float* __restrict__ pred, const float* __restrict__ gt,
    const int* __restrict__ hoff, const int* __restrict__ woff,
    float* __restrict__ out)
{
    // {p,g} packed as half2 -> one ds_read_b32 serves both arrays.
    __shared__ __half2 tile[TH * TW];   // 48*104*4 = 19968 B
    __shared__ float wsum[8];

    const int t  = threadIdx.x;
    const int bx = blockIdx.x;    // 0..7   j-tile
    const int by = blockIdx.y;    // 0..58  i-tile
    const int b  = blockIdx.z;    // 0..3   batch
    const int I0 = by * TI;
    const int J0 = bx * TJ;

    const float* pb_ = pred + b * (W * W);
    const float* gb_ = gt   + b * (W * W);

    // ---- stage input tile (rows always in range; cols clamped) ----
    for (int e = t; e < TH * TW; e += 512) {
        const int row = e / TW;
        const int col = e - row * TW;
        const int gr  = I0 + row;                      // <= 511 always
        int gc        = J0 + col; gc = gc < 511 ? gc : 511;
        const int gi  = gr * W + gc;
        tile[e] = __floats2half2_rn(pb_[gi], gb_[gi]);
    }
    __syncthreads();

    // ---- one pixel per thread: (ii, jj); lane-consecutive j -> conflict-free
    const int jj = t & 63;
    const int ii = t >> 6;                // 0..7
    const bool valid = (J0 + jj) < Wb;    // i always valid (59*8 = 472)

    const int base0 = (SPAN + ii) * TW + (SPAN + jj);
    const __half2 c0 = tile[base0];

    // ---- pass 1: read each shifted px ONCE, cache diff {dp,dg} in regs ----
    __half2 d[REPEAT];                    // target: 90 resident VGPRs
    __half2 sA = __floats2half2_rn(0.f, 0.f), sB = sA;
    #pragma unroll
    for (int r = 0; r < REPEAT; ++r) {
        const int off = hoff[r] * TW + woff[r];        // uniform (s_load+SALU)
        d[r] = __hsub2(c0, tile[base0 + off]);         // v_add + ds_read_b32
        if (r & 1) sB = __hfma2(d[r], d[r], sB);
        else       sA = __hfma2(d[r], d[r], sA);
    }

    // ---- pin the 90 diffs into VGPRs: forbids rematerializing the ds_reads
    //      in pass 2 (the compiler otherwise re-reads LDS; rounds 4/5). ----
    #pragma unroll
    for (int r = 0; r < REPEAT; ++r) {
        unsigned int du = __builtin_bit_cast(unsigned int, d[r]);
        asm volatile("" : "+v"(du));
        d[r] = __builtin_bit_cast(__half2, du);
    }

    const float ssp = __half2float(__low2half(sA))  + __half2float(__low2half(sB));
    const float ssg = __half2float(__high2half(sA)) + __half2float(__high2half(sB));

    const float invp = (ssp == 0.f) ? 1.f : rsqrtf(ssp);
    const float invg = (ssg == 0.f) ? 1.f : rsqrtf(ssg);

    // |dp*invp - dg*invg| = invp * |dp - (invg/invp)*dg|
    const __half nr = __float2half(-(invg / invp));

    // ---- pass 2: pure register math, 2 VALU per shift ----
    __half aA = __float2half(0.f), aB = aA;
    #pragma unroll
    for (int r = 0; r < REPEAT; ++r) {
        // s = dp + nr*dg  (dp = lo half, dg = hi half; op_sel picks halves)
        const __half s = __hfma(nr, __high2half(d[r]), __low2half(d[r]));
        if (r & 1) aB = __hadd(aB, __habs(s));
        else       aA = __hadd(aA, __habs(s));
    }
    const float l = invp * (__half2float(aA) + __half2float(aB));

    float lsum = valid ? l : 0.f;

    // ---- reduction: wave shuffle -> LDS -> one atomic per block ----
    #pragma unroll
    for (int o = 32; o > 0; o >>= 1) lsum += __shfl_down(lsum, o, 64);

    const int lane = t & 63;
    const int wid  = t >> 6;              // 0..7
    if (lane == 0) wsum[wid] = lsum;
    __syncthreads();

    if (t == 0) {
        float s = 0.f;
        #pragma unroll
        for (int k = 0; k < 8; ++k) s += wsum[k];
        constexpr float scale = 1.0f / (4.0f * 472.0f * 472.0f * 90.0f);
        atomicAdd(out, s * scale);
    }
}

extern "C" void kernel_launch(void* const* d_in, const int* in_sizes, int n_in,
                              void* d_out, int out_size, void* d_ws, size_t ws_size,
                              hipStream_t stream) {
    const float* pred = (const float*)d_in[0];
    const float* gt   = (const float*)d_in[1];
    const int* hoff   = (const int*)d_in[2];
    const int* woff   = (const int*)d_in[3];
    float* out = (float*)d_out;

    // Harness poisons d_out once and never re-poisons between graph replays:
    // zero it on-stream every call (graph-capturable).
    hipMemsetAsync(out, 0, sizeof(float), stream);

    dim3 grid(8, 59, 4);   // (472/64 ceil, 472/8, B)
    rd_loss_kernel<<<grid, 512, 0, stream>>>(pred, gt, hoff, woff, out);
}